// Round 1
// 249.249 us; speedup vs baseline: 1.0126x; 1.0126x over previous
//
#include <hip/hip_runtime.h>
#include <stdint.h>
#include <stddef.h>

// ============================================================================
// R9: latency-bound gemms -> 128x64 tiles (2x blocks/CU: gemm2 1->2/CU,
// gemm1 2.25->4.5/CU) + double-buffered 2-phase prefetch (issue tile t+1's
// global_load_lds BEFORE computing tile t; single barrier+drain per K-step).
// R8's async staging alone was neutral (252.4 vs 253.1) because at 1 block/CU
// the stage->drain->compute chain is fully serial; this overlaps it in-block.
// Everything except gemm_bt (+ its grids) byte-identical to R8.
// ============================================================================

typedef __attribute__((ext_vector_type(8))) __bf16 bf16x8;
typedef __attribute__((ext_vector_type(4))) float  floatx4;

#define N_NODES 256
#define F_IN    512
#define B_BATCH 4096
#define C_OUT   1000
#define NT      9
#define SCOLS   (N_NODES * NT)   // 2304
#define KPACK   (N_NODES * 4)    // 1024
#define OUT_N   4096000

__device__ __forceinline__ unsigned short f2us(float f) {  // bf16 RNE
  unsigned int v; __builtin_memcpy(&v, &f, sizeof(v));
  unsigned int r = (v + 0x7FFFu + ((v >> 16) & 1u)) >> 16;
  return (unsigned short)r;
}
__device__ __forceinline__ float us2f(unsigned short u) {
  unsigned int v = ((unsigned int)u) << 16;
  float f; __builtin_memcpy(&f, &v, sizeof(f)); return f;
}
__device__ __forceinline__ void async_ld16(const void* g, void* l) {
  __builtin_amdgcn_global_load_lds(
      (const __attribute__((address_space(1))) unsigned int*)g,
      (__attribute__((address_space(3))) unsigned int*)l, 16, 0, 0);
}

// ---------------------------------------------------------------------------
// Kernel 1: adjacency + folds + bias9 + biasc. One block, 256 threads. fp32 in.
// ---------------------------------------------------------------------------
__global__ __launch_bounds__(256)
void setup_kernel(const float* __restrict__ adj_w,
                  const float* __restrict__ basis,
                  const float* __restrict__ q_w,
                  const float* __restrict__ q_b,
                  const float* __restrict__ k_w,
                  const float* __restrict__ k_b,
                  const float* __restrict__ V_slow,
                  const float* __restrict__ sem_mem,
                  const float* __restrict__ mix_w,
                  const float* __restrict__ mix_b,
                  const float* __restrict__ b_in,
                  const float* __restrict__ b_out,
                  float* __restrict__ adjw, int* __restrict__ adjidx,
                  float* __restrict__ vecs,   // [9][64]
                  float* __restrict__ qbK,    // [4]
                  float* __restrict__ misc,   // [0]=mix_b
                  float* __restrict__ bias9,  // [256][9]
                  float* __restrict__ biasc)  // [1000]
{
  __shared__ float K4[4 * 64];
  __shared__ float KQ[4 * 64];
  __shared__ float A1s[4 * 64];
  __shared__ float vecsS[9 * 64];
  __shared__ float adjwS[256 * 4];
  __shared__ int   adjidxS[256 * 4];
  const int tid = threadIdx.x;

  for (int i = tid; i < C_OUT; i += 256) biasc[i] = b_out[i];

  // grid adjacency: order up, down, left, right == _grid_structs
  {
    const int n = tid, r = n >> 4, c = n & 15;
    int nb[4]; int cnt = 0;
    if (r > 0)  nb[cnt++] = n - 16;
    if (r < 15) nb[cnt++] = n + 16;
    if (c > 0)  nb[cnt++] = n - 1;
    if (c < 15) nb[cnt++] = n + 1;
    float wv[4] = {0.f, 0.f, 0.f, 0.f};
    float s = 0.f;
    for (int i = 0; i < cnt; ++i) {
      float sg = 1.f / (1.f + expf(-adj_w[(size_t)n * 256 + nb[i]]));
      wv[i] = sg; s += sg;
    }
    float deg = fmaxf(s, 1e-6f);
    int over = 0;
    for (int i = 0; i < cnt; ++i) { wv[i] /= deg; over += (wv[i] > 0.1f) ? 1 : 0; }
    if (over < 1) wv[0] = fmaxf(wv[0], 0.5f);
    for (int i = cnt; i < 4; ++i) nb[i] = n;    // pad, weight 0
    for (int i = 0; i < 4; ++i) {
      adjw[n * 4 + i] = wv[i];  adjidx[n * 4 + i] = nb[i];
      adjwS[n * 4 + i] = wv[i]; adjidxS[n * 4 + i] = nb[i];
    }
  }
  // K4[j][d] = basis_j · k_w[d,:] + k_b[d]
  {
    const int j = tid >> 6, d = tid & 63;
    float acc = k_b[d];
    for (int e = 0; e < 64; ++e) acc += basis[j * 64 + e] * k_w[d * 64 + e];
    K4[j * 64 + d] = acc;
  }
  __syncthreads();
  // KQ[j][e] = sum_d K4[j][d] q_w[d,e];  qbK[j] = q_b·K4_j;  mix_b
  {
    const int j = tid >> 6, e = tid & 63;
    float acc = 0.f;
    for (int d = 0; d < 64; ++d) acc += K4[j * 64 + d] * q_w[d * 64 + e];
    KQ[j * 64 + e] = acc;
    if (tid < 4) {
      float q = 0.f;
      for (int d = 0; d < 64; ++d) q += q_b[d] * K4[tid * 64 + d];
      qbK[tid] = q;
    }
    if (tid == 0) misc[0] = mix_b[0];
  }
  __syncthreads();
  // A1[j][e] = sum_d KQ[j][d] V_slow[d,e];  mw2[e] = sum_d mix_w[d] V_slow[d,e]
  {
    const int j = tid >> 6, e = tid & 63;
    float acc = 0.f;
    for (int d = 0; d < 64; ++d) acc += KQ[j * 64 + d] * V_slow[d * 64 + e];
    A1s[j * 64 + e] = acc;
    vecsS[j * 64 + e] = acc;
    if (tid < 64) {
      float mm = 0.f;
      for (int d = 0; d < 64; ++d) mm += mix_w[d] * V_slow[d * 64 + tid];
      vecsS[8 * 64 + tid] = mm;
    }
  }
  __syncthreads();
  // A2[j][f] = sum_e A1[j][e] sem_mem[e,f]
  {
    const int j = tid >> 6, f = tid & 63;
    float acc = 0.f;
    for (int e = 0; e < 64; ++e) acc += A1s[j * 64 + e] * sem_mem[e * 64 + f];
    vecsS[(4 + j) * 64 + f] = acc;
  }
  __syncthreads();
  for (int i = tid; i < NT * 64; i += 256) vecs[i] = vecsS[i];
  // bias9[n][t] = sum_d (sum_k aw*b_in[idx*64+d]) * vec_t[d]
  {
    const int n = tid;
    float bt[9] = {0,0,0,0,0,0,0,0,0};
    for (int d = 0; d < 64; ++d) {
      float v = 0.f;
      for (int k = 0; k < 4; ++k)
        v += adjwS[n * 4 + k] * b_in[(size_t)adjidxS[n * 4 + k] * 64 + d];
      #pragma unroll
      for (int t = 0; t < 9; ++t) bt[t] += v * vecsS[t * 64 + d];
    }
    for (int t = 0; t < 9; ++t) bias9[n * 9 + t] = bt[t];
  }
}

// ---------------------------------------------------------------------------
// Kernel 2: x chunk -> bf16 (8 elems/thread)
// ---------------------------------------------------------------------------
__global__ __launch_bounds__(256)
void convert_x_kernel(const float* __restrict__ x, unsigned short* __restrict__ xb)
{
  const size_t i0 = ((size_t)blockIdx.x * 256 + threadIdx.x) * 8;
  const float4 a = *(const float4*)(x + i0);
  const float4 b = *(const float4*)(x + i0 + 4);
  ushort4 o0, o1;
  o0.x = f2us(a.x); o0.y = f2us(a.y); o0.z = f2us(a.z); o0.w = f2us(a.w);
  o1.x = f2us(b.x); o1.y = f2us(b.y); o1.z = f2us(b.z); o1.w = f2us(b.w);
  *(ushort4*)(xb + i0)     = o0;
  *(ushort4*)(xb + i0 + 4) = o1;
}

// ---------------------------------------------------------------------------
// Kernel 3: T[m*9+t][f] = sum_d vec_t[d] * W_in[m*64+d, f]   (fp32)
// ---------------------------------------------------------------------------
__global__ __launch_bounds__(512)
void build_T_kernel(const float* __restrict__ W_in,
                    const float* __restrict__ vecs,
                    float* __restrict__ T)
{
  __shared__ float vl[NT * 64];
  const int m = blockIdx.x, f = threadIdx.x;
  for (int i = threadIdx.x; i < NT * 64; i += 512) vl[i] = vecs[i];
  __syncthreads();
  float acc[NT] = {0,0,0,0,0,0,0,0,0};
  for (int d = 0; d < 64; ++d) {
    float wv = W_in[(size_t)(m * 64 + d) * F_IN + f];
    #pragma unroll
    for (int t = 0; t < NT; ++t) acc[t] += wv * vl[t * 64 + d];
  }
  for (int t = 0; t < NT; ++t) T[(size_t)(m * NT + t) * F_IN + f] = acc[t];
}

// ---------------------------------------------------------------------------
// Kernel 4: U[n*9+t][f] = sum_k adjw[n][k] * T[idx[n][k]*9+t][f]  (bf16)
// ---------------------------------------------------------------------------
__global__ __launch_bounds__(512)
void build_U_kernel(const float* __restrict__ T,
                    const float* __restrict__ adjw,
                    const int* __restrict__ adjidx,
                    unsigned short* __restrict__ U)
{
  const int n = blockIdx.x, f = threadIdx.x;
  const float w0 = adjw[n * 4 + 0], w1 = adjw[n * 4 + 1];
  const float w2 = adjw[n * 4 + 2], w3 = adjw[n * 4 + 3];
  const int i0 = adjidx[n * 4 + 0], i1 = adjidx[n * 4 + 1];
  const int i2 = adjidx[n * 4 + 2], i3 = adjidx[n * 4 + 3];
  #pragma unroll
  for (int t = 0; t < NT; ++t) {
    float u = w0 * T[(size_t)(i0 * NT + t) * F_IN + f]
            + w1 * T[(size_t)(i1 * NT + t) * F_IN + f]
            + w2 * T[(size_t)(i2 * NT + t) * F_IN + f]
            + w3 * T[(size_t)(i3 * NT + t) * F_IN + f];
    U[(size_t)(n * NT + t) * F_IN + f] = f2us(u);
  }
}

// ---------------------------------------------------------------------------
// Kernel 5: PT[c][n*4+j] = basis_j · W_out[c, n*64:+64]  (bf16); pad rows zero
// ---------------------------------------------------------------------------
__global__ __launch_bounds__(256)
void build_PT_kernel(const float* __restrict__ W_out,
                     const float* __restrict__ basis,
                     unsigned short* __restrict__ PT)
{
  const int c = blockIdx.x, tid = threadIdx.x;
  if (c >= C_OUT) {
    for (int i = tid; i < KPACK; i += 256) PT[(size_t)c * KPACK + i] = 0;
    return;
  }
  __shared__ __align__(16) float row[16384];   // one W_out row, 64 KB LDS
  __shared__ float bas[4 * 64];
  const float4* src = (const float4*)(W_out + (size_t)c * 16384);
  float4* dst = (float4*)row;
  for (int i = tid; i < 4096; i += 256) dst[i] = src[i];
  bas[tid] = basis[tid];
  __syncthreads();
  const int n = tid;
  float a0 = 0.f, a1 = 0.f, a2 = 0.f, a3 = 0.f;
  for (int dd = 0; dd < 64; ++dd) {
    int d = (dd + n) & 63;                  // rotate: 2-way banking (free)
    float wv = row[n * 64 + d];
    a0 += wv * bas[0 * 64 + d];
    a1 += wv * bas[1 * 64 + d];
    a2 += wv * bas[2 * 64 + d];
    a3 += wv * bas[3 * 64 + d];
  }
  unsigned short* p = PT + (size_t)c * KPACK + n * 4;
  p[0] = f2us(a0); p[1] = f2us(a1); p[2] = f2us(a2); p[3] = f2us(a3);
}

// ---------------------------------------------------------------------------
// 128x64 bf16 MFMA GEMM, C = A @ B^T, double-buffered 2-phase prefetch:
// issue tile t+1's global_load_lds, compute tile t, barrier (implicit
// vmcnt(0)+lgkmcnt(0) drain), swap. A:[M][K], B:[NC][K] bf16.
// FINAL=false: bf16 store. FINAL=true: fp32 + bias, col<ncol guard.
// Epilogue mapping: C/D col=lane&15, row=(lane>>4)*4+reg (validated R3/R4).
// ---------------------------------------------------------------------------
template <int K, bool FINAL>
__global__ __launch_bounds__(256)
void gemm_bt(const unsigned short* __restrict__ A,
             const unsigned short* __restrict__ B,
             unsigned short* __restrict__ Cb, float* __restrict__ Cf,
             int ncol, const float* __restrict__ biasf)
{
  __shared__ __align__(16) unsigned short As[2][128 * 64];  // 2 x 16 KB
  __shared__ __align__(16) unsigned short Bs[2][64 * 64];   // 2 x  8 KB
  const int tid  = threadIdx.x;
  const int lane = tid & 63;
  const int wave = tid >> 6;
  const int m0 = blockIdx.x * 128;
  const int n0 = blockIdx.y * 64;
  const int wm = (wave >> 1) * 64;
  const int wn = (wave & 1) * 32;

  floatx4 acc[4][2];
  #pragma unroll
  for (int i = 0; i < 4; ++i)
    #pragma unroll
    for (int j = 0; j < 2; ++j) acc[i][j] = (floatx4){0.f, 0.f, 0.f, 0.f};

  const int NK = K / 64;
  int cur = 0;

  // staging: LDS dest is wave-uniform base + lane*16 (HW rule); lane L of
  // chunk-group lands linearly so row r = chunk>>3, k-off = (chunk&7)*8.
  auto stage = [&](int s, int kt) {
    const int k0 = kt * 64;
    #pragma unroll
    for (int it = 0; it < 4; ++it) {           // A: 128x64 = 1024 granules
      const int chunk = it * 256 + tid;
      async_ld16(A + (size_t)(m0 + (chunk >> 3)) * K + k0 + ((chunk & 7) << 3),
                 &As[s][(it * 256 + wave * 64) * 8]);
    }
    #pragma unroll
    for (int it = 0; it < 2; ++it) {           // B: 64x64 = 512 granules
      const int chunk = it * 256 + tid;
      async_ld16(B + (size_t)(n0 + (chunk >> 3)) * K + k0 + ((chunk & 7) << 3),
                 &Bs[s][(it * 256 + wave * 64) * 8]);
    }
  };

  stage(0, 0);
  __syncthreads();                             // tile 0 resident

  for (int kt = 0; kt < NK; ++kt) {
    if (kt + 1 < NK) stage(cur ^ 1, kt + 1);   // prefetch flies under compute
    const int lrow = lane & 15;
    #pragma unroll
    for (int kk = 0; kk < 2; ++kk) {
      const int lk = kk * 32 + (lane >> 4) * 8;
      bf16x8 af[4], bfr[2];
      #pragma unroll
      for (int i = 0; i < 4; ++i)
        af[i] = *(const bf16x8*)&As[cur][(wm + i * 16 + lrow) * 64 + lk];
      #pragma unroll
      for (int j = 0; j < 2; ++j)
        bfr[j] = *(const bf16x8*)&Bs[cur][(wn + j * 16 + lrow) * 64 + lk];
      #pragma unroll
      for (int i = 0; i < 4; ++i)
        #pragma unroll
        for (int j = 0; j < 2; ++j)
          acc[i][j] = __builtin_amdgcn_mfma_f32_16x16x32_bf16(af[i], bfr[j], acc[i][j], 0, 0, 0);
    }
    if (kt + 1 < NK) {
      __syncthreads();   // drains prefetch vmcnt; all waves done reading cur
      cur ^= 1;
    }
  }

  // epilogue: C/D layout col = lane&15, row = (lane>>4)*4 + reg
  const int rq = (lane >> 4) * 4;
  const int cq = lane & 15;
  #pragma unroll
  for (int j = 0; j < 2; ++j) {
    const int col = n0 + wn + j * 16 + cq;
    if (FINAL && col >= ncol) continue;
    const float bv2 = FINAL ? biasf[col] : 0.f;
    #pragma unroll
    for (int i = 0; i < 4; ++i)
      #pragma unroll
      for (int r = 0; r < 4; ++r) {
        const int rowi = m0 + wm + i * 16 + rq + r;
        if (FINAL) Cf[(size_t)rowi * ncol + col] = acc[i][j][r] + bv2;
        else       Cb[(size_t)rowi * ncol + col] = f2us(acc[i][j][r]);
      }
  }
}

// ---------------------------------------------------------------------------
// Kernel 7: per-(b,n) mix/attn/softmax -> w bf16 [BCH][1024]
// ---------------------------------------------------------------------------
__global__ __launch_bounds__(256)
void softmax_kernel(const unsigned short* __restrict__ scores,  // bf16 [BCH][2304]
                    const float* __restrict__ bias9,
                    const float* __restrict__ qbK,
                    const float* __restrict__ misc,
                    unsigned short* __restrict__ w)
{
  const int b = blockIdx.x, n = threadIdx.x;
  const unsigned short* s = scores + (size_t)b * SCOLS + n * NT;
  const float* bs = bias9 + n * NT;
  const float mixb = misc[0];
  const float q0 = qbK[0], q1 = qbK[1], q2 = qbK[2], q3 = qbK[3];
  const float mix = 1.f / (1.f + expf(-(us2f(s[8]) + bs[8] + mixb)));
  const float om = 1.f - mix;
  const float inv_s = 1.f / (8.f + 1e-8f);
  float a0 = (mix * (us2f(s[0]) + bs[0]) + om * (us2f(s[4]) + bs[4]) + q0) * inv_s;
  float a1 = (mix * (us2f(s[1]) + bs[1]) + om * (us2f(s[5]) + bs[5]) + q1) * inv_s;
  float a2 = (mix * (us2f(s[2]) + bs[2]) + om * (us2f(s[6]) + bs[6]) + q2) * inv_s;
  float a3 = (mix * (us2f(s[3]) + bs[3]) + om * (us2f(s[7]) + bs[7]) + q3) * inv_s;
  const float mx = fmaxf(fmaxf(a0, a1), fmaxf(a2, a3));
  const float e0 = expf(a0 - mx), e1 = expf(a1 - mx);
  const float e2 = expf(a2 - mx), e3 = expf(a3 - mx);
  const float rs = 1.f / (e0 + e1 + e2 + e3);
  ushort4 pk;
  pk.x = f2us(e0 * rs); pk.y = f2us(e1 * rs);
  pk.z = f2us(e2 * rs); pk.w = f2us(e3 * rs);
  *(ushort4*)(w + (size_t)b * KPACK + n * 4) = pk;
}

// ---------------------------------------------------------------------------
__global__ __launch_bounds__(256)
void sentinel_kernel(float* __restrict__ out, float val) {
  const size_t i = (size_t)blockIdx.x * 256 + threadIdx.x;
  if (i < OUT_N) out[i] = val;
}

// ---------------------------------------------------------------------------
extern "C" void kernel_launch(void* const* d_in, const int* in_sizes, int n_in,
                              void* d_out, int out_size, void* d_ws, size_t ws_size,
                              hipStream_t stream)
{
  static const int EXP[16] = {2097152, 8388608, 16384, 65536, 65536, 4096, 4096,
                              64, 1, 256, 4096, 64, 4096, 64, 16384000, 1000};
  bool ok = (n_in == 16) && (out_size == OUT_N);
  if (ok) for (int i = 0; i < 16; ++i) ok = ok && (in_sizes[i] == EXP[i]);
  float* out32 = (float*)d_out;
  if (!ok) {
    sentinel_kernel<<<dim3(16000), dim3(256), 0, stream>>>(out32, 8192.f);
    return;
  }

  const float* x_f    = (const float*)d_in[0];
  const float* Win_f  = (const float*)d_in[1];
  const float* bin_f  = (const float*)d_in[2];
  const float* adjW_f = (const float*)d_in[3];
  const float* Vs_f   = (const float*)d_in[5];
  const float* sem_f  = (const float*)d_in[6];
  const float* mw_f   = (const float*)d_in[7];
  const float* mb_f   = (const float*)d_in[8];
  const float* bas_f  = (const float*)d_in[9];
  const float* qw_f   = (const float*)d_in[10];
  const float* qb_f   = (const float*)d_in[11];
  const float* kw_f   = (const float*)d_in[12];
  const float* kb_f   = (const float*)d_in[13];
  const float* Wout_f = (const float*)d_in[14];
  const float* bout_f = (const float*)d_in[15];

  // adaptive batch chunk from ws_size (>= 12.4 MB fallback always fits)
  int BCH = 1024;
  {
    auto need = [](size_t b) {
      size_t ts = 4718592 > 4608 * b ? 4718592 : 4608 * b;  // T union scores
      return (size_t)32768 + 2359296 + 2097152 + ts + 1024 * b + 2048 * b;
    };
    if (ws_size >= need(4096)) BCH = 4096;
    else if (ws_size >= need(2048)) BCH = 2048;
  }
  const int NCH = B_BATCH / BCH;
  if (ws_size < (size_t)12353536) {
    sentinel_kernel<<<dim3(16000), dim3(256), 0, stream>>>(
        out32, 16.f * (float)(ws_size >> 20));
    return;
  }

  uint8_t* ws = (uint8_t*)d_ws;
  float* adjw   = (float*)(ws + 0);          // 4 KB
  int*   adjidx = (int*)  (ws + 4096);       // 4 KB
  float* vecs   = (float*)(ws + 8192);       // 2304 B
  float* qbK    = (float*)(ws + 10496);      // 16 B
  float* misc   = (float*)(ws + 10560);      // 4 B
  float* bias9  = (float*)(ws + 12288);      // 9216 B
  float* biasc  = (float*)(ws + 21504);      // 4000 B
  size_t off = 32768;
  unsigned short* U  = (unsigned short*)(ws + off); off += 2359296;
  unsigned short* PT = (unsigned short*)(ws + off); off += 2097152;
  float*          T  = (float*)(ws + off);                       // union:
  unsigned short* sc = (unsigned short*)(ws + off);              // T | scores
  off += (4718592 > (size_t)4608 * BCH ? 4718592 : (size_t)4608 * BCH);
  unsigned short* xb = (unsigned short*)(ws + off); off += (size_t)1024 * BCH;
  unsigned short* wq = (unsigned short*)(ws + off);

  setup_kernel<<<dim3(1), dim3(256), 0, stream>>>(
      adjW_f, bas_f, qw_f, qb_f, kw_f, kb_f, Vs_f, sem_f, mw_f, mb_f,
      bin_f, bout_f, adjw, adjidx, vecs, qbK, misc, bias9, biasc);
  build_T_kernel<<<dim3(256), dim3(512), 0, stream>>>(Win_f, vecs, T);
  build_U_kernel<<<dim3(256), dim3(512), 0, stream>>>(T, adjw, adjidx, U);
  build_PT_kernel<<<dim3(1024), dim3(256), 0, stream>>>(Wout_f, bas_f, PT);

  for (int ch = 0; ch < NCH; ++ch) {
    const size_t row0 = (size_t)ch * BCH;
    convert_x_kernel<<<dim3(BCH / 4), dim3(256), 0, stream>>>(
        x_f + row0 * F_IN, xb);
    gemm_bt<F_IN, false><<<dim3(BCH / 128, SCOLS / 64), dim3(256), 0, stream>>>(
        xb, U, sc, nullptr, SCOLS, nullptr);
    softmax_kernel<<<dim3(BCH), dim3(256), 0, stream>>>(sc, bias9, qbK, misc, wq);
    gemm_bt<KPACK, true><<<dim3(BCH / 128, KPACK / 64), dim3(256), 0, stream>>>(
        wq, PT, nullptr, out32 + row0 * C_OUT, C_OUT, biasc);
  }
}

// Round 2
// 243.674 us; speedup vs baseline: 1.0358x; 1.0229x over previous
//
#include <hip/hip_runtime.h>
#include <stdint.h>
#include <stddef.h>

// ============================================================================
// R10: gemm_bt gets (a) T2 XOR granule swizzle — the [row][64]-bf16 tile had a
// 16-way bank conflict on every ds_read_b128 (row stride 128 B; only 16/32
// banks active). Swizzle g^=(row&7) applied to the GLOBAL source address of
// global_load_lds (linear LDS dest, rule #21) and to the read address.
// (b) T4 counted vmcnt: 2 raw s_barriers per K-step + s_waitcnt vmcnt(6);
// tile kt's loads were issued one full iteration earlier so the wait is ~free,
// and the prefetch survives the barrier (R9's __syncthreads drained it).
// Everything except gemm_bt byte-identical to R9.
// ============================================================================

typedef __attribute__((ext_vector_type(8))) __bf16 bf16x8;
typedef __attribute__((ext_vector_type(4))) float  floatx4;

#define N_NODES 256
#define F_IN    512
#define B_BATCH 4096
#define C_OUT   1000
#define NT      9
#define SCOLS   (N_NODES * NT)   // 2304
#define KPACK   (N_NODES * 4)    // 1024
#define OUT_N   4096000

__device__ __forceinline__ unsigned short f2us(float f) {  // bf16 RNE
  unsigned int v; __builtin_memcpy(&v, &f, sizeof(v));
  unsigned int r = (v + 0x7FFFu + ((v >> 16) & 1u)) >> 16;
  return (unsigned short)r;
}
__device__ __forceinline__ float us2f(unsigned short u) {
  unsigned int v = ((unsigned int)u) << 16;
  float f; __builtin_memcpy(&f, &v, sizeof(f)); return f;
}
__device__ __forceinline__ void async_ld16(const void* g, void* l) {
  __builtin_amdgcn_global_load_lds(
      (const __attribute__((address_space(1))) unsigned int*)g,
      (__attribute__((address_space(3))) unsigned int*)l, 16, 0, 0);
}

// ---------------------------------------------------------------------------
// Kernel 1: adjacency + folds + bias9 + biasc. One block, 256 threads. fp32 in.
// ---------------------------------------------------------------------------
__global__ __launch_bounds__(256)
void setup_kernel(const float* __restrict__ adj_w,
                  const float* __restrict__ basis,
                  const float* __restrict__ q_w,
                  const float* __restrict__ q_b,
                  const float* __restrict__ k_w,
                  const float* __restrict__ k_b,
                  const float* __restrict__ V_slow,
                  const float* __restrict__ sem_mem,
                  const float* __restrict__ mix_w,
                  const float* __restrict__ mix_b,
                  const float* __restrict__ b_in,
                  const float* __restrict__ b_out,
                  float* __restrict__ adjw, int* __restrict__ adjidx,
                  float* __restrict__ vecs,   // [9][64]
                  float* __restrict__ qbK,    // [4]
                  float* __restrict__ misc,   // [0]=mix_b
                  float* __restrict__ bias9,  // [256][9]
                  float* __restrict__ biasc)  // [1000]
{
  __shared__ float K4[4 * 64];
  __shared__ float KQ[4 * 64];
  __shared__ float A1s[4 * 64];
  __shared__ float vecsS[9 * 64];
  __shared__ float adjwS[256 * 4];
  __shared__ int   adjidxS[256 * 4];
  const int tid = threadIdx.x;

  for (int i = tid; i < C_OUT; i += 256) biasc[i] = b_out[i];

  // grid adjacency: order up, down, left, right == _grid_structs
  {
    const int n = tid, r = n >> 4, c = n & 15;
    int nb[4]; int cnt = 0;
    if (r > 0)  nb[cnt++] = n - 16;
    if (r < 15) nb[cnt++] = n + 16;
    if (c > 0)  nb[cnt++] = n - 1;
    if (c < 15) nb[cnt++] = n + 1;
    float wv[4] = {0.f, 0.f, 0.f, 0.f};
    float s = 0.f;
    for (int i = 0; i < cnt; ++i) {
      float sg = 1.f / (1.f + expf(-adj_w[(size_t)n * 256 + nb[i]]));
      wv[i] = sg; s += sg;
    }
    float deg = fmaxf(s, 1e-6f);
    int over = 0;
    for (int i = 0; i < cnt; ++i) { wv[i] /= deg; over += (wv[i] > 0.1f) ? 1 : 0; }
    if (over < 1) wv[0] = fmaxf(wv[0], 0.5f);
    for (int i = cnt; i < 4; ++i) nb[i] = n;    // pad, weight 0
    for (int i = 0; i < 4; ++i) {
      adjw[n * 4 + i] = wv[i];  adjidx[n * 4 + i] = nb[i];
      adjwS[n * 4 + i] = wv[i]; adjidxS[n * 4 + i] = nb[i];
    }
  }
  // K4[j][d] = basis_j · k_w[d,:] + k_b[d]
  {
    const int j = tid >> 6, d = tid & 63;
    float acc = k_b[d];
    for (int e = 0; e < 64; ++e) acc += basis[j * 64 + e] * k_w[d * 64 + e];
    K4[j * 64 + d] = acc;
  }
  __syncthreads();
  // KQ[j][e] = sum_d K4[j][d] q_w[d,e];  qbK[j] = q_b·K4_j;  mix_b
  {
    const int j = tid >> 6, e = tid & 63;
    float acc = 0.f;
    for (int d = 0; d < 64; ++d) acc += K4[j * 64 + d] * q_w[d * 64 + e];
    KQ[j * 64 + e] = acc;
    if (tid < 4) {
      float q = 0.f;
      for (int d = 0; d < 64; ++d) q += q_b[d] * K4[tid * 64 + d];
      qbK[tid] = q;
    }
    if (tid == 0) misc[0] = mix_b[0];
  }
  __syncthreads();
  // A1[j][e] = sum_d KQ[j][d] V_slow[d,e];  mw2[e] = sum_d mix_w[d] V_slow[d,e]
  {
    const int j = tid >> 6, e = tid & 63;
    float acc = 0.f;
    for (int d = 0; d < 64; ++d) acc += KQ[j * 64 + d] * V_slow[d * 64 + e];
    A1s[j * 64 + e] = acc;
    vecsS[j * 64 + e] = acc;
    if (tid < 64) {
      float mm = 0.f;
      for (int d = 0; d < 64; ++d) mm += mix_w[d] * V_slow[d * 64 + tid];
      vecsS[8 * 64 + tid] = mm;
    }
  }
  __syncthreads();
  // A2[j][f] = sum_e A1[j][e] sem_mem[e,f]
  {
    const int j = tid >> 6, f = tid & 63;
    float acc = 0.f;
    for (int e = 0; e < 64; ++e) acc += A1s[j * 64 + e] * sem_mem[e * 64 + f];
    vecsS[(4 + j) * 64 + f] = acc;
  }
  __syncthreads();
  for (int i = tid; i < NT * 64; i += 256) vecs[i] = vecsS[i];
  // bias9[n][t] = sum_d (sum_k aw*b_in[idx*64+d]) * vec_t[d]
  {
    const int n = tid;
    float bt[9] = {0,0,0,0,0,0,0,0,0};
    for (int d = 0; d < 64; ++d) {
      float v = 0.f;
      for (int k = 0; k < 4; ++k)
        v += adjwS[n * 4 + k] * b_in[(size_t)adjidxS[n * 4 + k] * 64 + d];
      #pragma unroll
      for (int t = 0; t < 9; ++t) bt[t] += v * vecsS[t * 64 + d];
    }
    for (int t = 0; t < 9; ++t) bias9[n * 9 + t] = bt[t];
  }
}

// ---------------------------------------------------------------------------
// Kernel 2: x chunk -> bf16 (8 elems/thread)
// ---------------------------------------------------------------------------
__global__ __launch_bounds__(256)
void convert_x_kernel(const float* __restrict__ x, unsigned short* __restrict__ xb)
{
  const size_t i0 = ((size_t)blockIdx.x * 256 + threadIdx.x) * 8;
  const float4 a = *(const float4*)(x + i0);
  const float4 b = *(const float4*)(x + i0 + 4);
  ushort4 o0, o1;
  o0.x = f2us(a.x); o0.y = f2us(a.y); o0.z = f2us(a.z); o0.w = f2us(a.w);
  o1.x = f2us(b.x); o1.y = f2us(b.y); o1.z = f2us(b.z); o1.w = f2us(b.w);
  *(ushort4*)(xb + i0)     = o0;
  *(ushort4*)(xb + i0 + 4) = o1;
}

// ---------------------------------------------------------------------------
// Kernel 3: T[m*9+t][f] = sum_d vec_t[d] * W_in[m*64+d, f]   (fp32)
// ---------------------------------------------------------------------------
__global__ __launch_bounds__(512)
void build_T_kernel(const float* __restrict__ W_in,
                    const float* __restrict__ vecs,
                    float* __restrict__ T)
{
  __shared__ float vl[NT * 64];
  const int m = blockIdx.x, f = threadIdx.x;
  for (int i = threadIdx.x; i < NT * 64; i += 512) vl[i] = vecs[i];
  __syncthreads();
  float acc[NT] = {0,0,0,0,0,0,0,0,0};
  for (int d = 0; d < 64; ++d) {
    float wv = W_in[(size_t)(m * 64 + d) * F_IN + f];
    #pragma unroll
    for (int t = 0; t < NT; ++t) acc[t] += wv * vl[t * 64 + d];
  }
  for (int t = 0; t < NT; ++t) T[(size_t)(m * NT + t) * F_IN + f] = acc[t];
}

// ---------------------------------------------------------------------------
// Kernel 4: U[n*9+t][f] = sum_k adjw[n][k] * T[idx[n][k]*9+t][f]  (bf16)
// ---------------------------------------------------------------------------
__global__ __launch_bounds__(512)
void build_U_kernel(const float* __restrict__ T,
                    const float* __restrict__ adjw,
                    const int* __restrict__ adjidx,
                    unsigned short* __restrict__ U)
{
  const int n = blockIdx.x, f = threadIdx.x;
  const float w0 = adjw[n * 4 + 0], w1 = adjw[n * 4 + 1];
  const float w2 = adjw[n * 4 + 2], w3 = adjw[n * 4 + 3];
  const int i0 = adjidx[n * 4 + 0], i1 = adjidx[n * 4 + 1];
  const int i2 = adjidx[n * 4 + 2], i3 = adjidx[n * 4 + 3];
  #pragma unroll
  for (int t = 0; t < NT; ++t) {
    float u = w0 * T[(size_t)(i0 * NT + t) * F_IN + f]
            + w1 * T[(size_t)(i1 * NT + t) * F_IN + f]
            + w2 * T[(size_t)(i2 * NT + t) * F_IN + f]
            + w3 * T[(size_t)(i3 * NT + t) * F_IN + f];
    U[(size_t)(n * NT + t) * F_IN + f] = f2us(u);
  }
}

// ---------------------------------------------------------------------------
// Kernel 5: PT[c][n*4+j] = basis_j · W_out[c, n*64:+64]  (bf16); pad rows zero
// ---------------------------------------------------------------------------
__global__ __launch_bounds__(256)
void build_PT_kernel(const float* __restrict__ W_out,
                     const float* __restrict__ basis,
                     unsigned short* __restrict__ PT)
{
  const int c = blockIdx.x, tid = threadIdx.x;
  if (c >= C_OUT) {
    for (int i = tid; i < KPACK; i += 256) PT[(size_t)c * KPACK + i] = 0;
    return;
  }
  __shared__ __align__(16) float row[16384];   // one W_out row, 64 KB LDS
  __shared__ float bas[4 * 64];
  const float4* src = (const float4*)(W_out + (size_t)c * 16384);
  float4* dst = (float4*)row;
  for (int i = tid; i < 4096; i += 256) dst[i] = src[i];
  bas[tid] = basis[tid];
  __syncthreads();
  const int n = tid;
  float a0 = 0.f, a1 = 0.f, a2 = 0.f, a3 = 0.f;
  for (int dd = 0; dd < 64; ++dd) {
    int d = (dd + n) & 63;                  // rotate: 2-way banking (free)
    float wv = row[n * 64 + d];
    a0 += wv * bas[0 * 64 + d];
    a1 += wv * bas[1 * 64 + d];
    a2 += wv * bas[2 * 64 + d];
    a3 += wv * bas[3 * 64 + d];
  }
  unsigned short* p = PT + (size_t)c * KPACK + n * 4;
  p[0] = f2us(a0); p[1] = f2us(a1); p[2] = f2us(a2); p[3] = f2us(a3);
}

// ---------------------------------------------------------------------------
// 128x64 bf16 MFMA GEMM, C = A @ B^T.
// T2: granule swizzle g^=(row&7) — LDS dest of global_load_lds stays linear,
//     the GLOBAL source granule is inverse-permuted (XOR is an involution),
//     reads apply the same XOR. 16-way bank conflict -> all 32 banks active.
// T4: counted s_waitcnt vmcnt(6) (6 = per-thread loads per stage) + raw
//     s_barrier pair per K-step; prefetch stays in flight across barriers.
//     Tile kt's loads were issued one iteration earlier -> wait is ~free.
// A:[M][K], B:[NC][K] bf16. FINAL=false: bf16 store. FINAL=true: fp32+bias.
// Epilogue mapping: C/D col=lane&15, row=(lane>>4)*4+reg (validated R3/R4).
// ---------------------------------------------------------------------------
template <int K, bool FINAL>
__global__ __launch_bounds__(256)
void gemm_bt(const unsigned short* __restrict__ A,
             const unsigned short* __restrict__ B,
             unsigned short* __restrict__ Cb, float* __restrict__ Cf,
             int ncol, const float* __restrict__ biasf)
{
  __shared__ __align__(16) unsigned short As[2][128 * 64];  // 2 x 16 KB
  __shared__ __align__(16) unsigned short Bs[2][64 * 64];   // 2 x  8 KB
  const int tid  = threadIdx.x;
  const int lane = tid & 63;
  const int wave = tid >> 6;
  const int m0 = blockIdx.x * 128;
  const int n0 = blockIdx.y * 64;
  const int wm = (wave >> 1) * 64;
  const int wn = (wave & 1) * 32;

  floatx4 acc[4][2];
  #pragma unroll
  for (int i = 0; i < 4; ++i)
    #pragma unroll
    for (int j = 0; j < 2; ++j) acc[i][j] = (floatx4){0.f, 0.f, 0.f, 0.f};

  const int NK = K / 64;

  // stage: LDS dest linear (wave-uniform base + lane*16, HW rule); global
  // source granule pre-swizzled so the XOR'd read below sees correct data.
  auto stage = [&](int s, int kt) {
    const int k0 = kt * 64;
    #pragma unroll
    for (int it = 0; it < 4; ++it) {           // A: 128 rows x 8 granules
      const int chunk = it * 256 + tid;
      const int r = chunk >> 3, g = chunk & 7;
      async_ld16(A + (size_t)(m0 + r) * K + k0 + ((g ^ (r & 7)) << 3),
                 &As[s][(it * 256 + wave * 64) * 8]);
    }
    #pragma unroll
    for (int it = 0; it < 2; ++it) {           // B: 64 rows x 8 granules
      const int chunk = it * 256 + tid;
      const int r = chunk >> 3, g = chunk & 7;
      async_ld16(B + (size_t)(n0 + r) * K + k0 + ((g ^ (r & 7)) << 3),
                 &Bs[s][(it * 256 + wave * 64) * 8]);
    }
  };

  stage(0, 0);                                 // 6 loads/thread in flight
  int cur = 0;

  for (int kt = 0; kt < NK; ++kt) {
    if (kt + 1 < NK) {
      stage(cur ^ 1, kt + 1);                  // outstanding: 12
      // wait for tile kt's 6 (oldest); kt+1's 6 stay in flight across barrier
      asm volatile("s_waitcnt vmcnt(6)" ::: "memory");
    } else {
      asm volatile("s_waitcnt vmcnt(0)" ::: "memory");
    }
    __builtin_amdgcn_s_barrier();              // all waves' kt loads resident

    const int lrow = lane & 15;
    const int ghi  = lane >> 4;                // granule base bits
    #pragma unroll
    for (int kk = 0; kk < 2; ++kk) {
      const int gbase = kk * 4 + ghi;          // logical granule 0..7
      bf16x8 af[4], bfr[2];
      #pragma unroll
      for (int i = 0; i < 4; ++i) {
        const int row = wm + i * 16 + lrow;
        af[i] = *(const bf16x8*)&As[cur][row * 64 + ((gbase ^ (row & 7)) << 3)];
      }
      #pragma unroll
      for (int j = 0; j < 2; ++j) {
        const int row = wn + j * 16 + lrow;
        bfr[j] = *(const bf16x8*)&Bs[cur][row * 64 + ((gbase ^ (row & 7)) << 3)];
      }
      #pragma unroll
      for (int i = 0; i < 4; ++i)
        #pragma unroll
        for (int j = 0; j < 2; ++j)
          acc[i][j] = __builtin_amdgcn_mfma_f32_16x16x32_bf16(af[i], bfr[j], acc[i][j], 0, 0, 0);
    }
    if (kt + 1 < NK) {
      __builtin_amdgcn_s_barrier();            // readers of cur done before
      cur ^= 1;                                // next iter stages into cur
    }
  }

  // epilogue: C/D layout col = lane&15, row = (lane>>4)*4 + reg
  const int rq = (lane >> 4) * 4;
  const int cq = lane & 15;
  #pragma unroll
  for (int j = 0; j < 2; ++j) {
    const int col = n0 + wn + j * 16 + cq;
    if (FINAL && col >= ncol) continue;
    const float bv2 = FINAL ? biasf[col] : 0.f;
    #pragma unroll
    for (int i = 0; i < 4; ++i)
      #pragma unroll
      for (int r = 0; r < 4; ++r) {
        const int rowi = m0 + wm + i * 16 + rq + r;
        if (FINAL) Cf[(size_t)rowi * ncol + col] = acc[i][j][r] + bv2;
        else       Cb[(size_t)rowi * ncol + col] = f2us(acc[i][j][r]);
      }
  }
}

// ---------------------------------------------------------------------------
// Kernel 7: per-(b,n) mix/attn/softmax -> w bf16 [BCH][1024]
// ---------------------------------------------------------------------------
__global__ __launch_bounds__(256)
void softmax_kernel(const unsigned short* __restrict__ scores,  // bf16 [BCH][2304]
                    const float* __restrict__ bias9,
                    const float* __restrict__ qbK,
                    const float* __restrict__ misc,
                    unsigned short* __restrict__ w)
{
  const int b = blockIdx.x, n = threadIdx.x;
  const unsigned short* s = scores + (size_t)b * SCOLS + n * NT;
  const float* bs = bias9 + n * NT;
  const float mixb = misc[0];
  const float q0 = qbK[0], q1 = qbK[1], q2 = qbK[2], q3 = qbK[3];
  const float mix = 1.f / (1.f + expf(-(us2f(s[8]) + bs[8] + mixb)));
  const float om = 1.f - mix;
  const float inv_s = 1.f / (8.f + 1e-8f);
  float a0 = (mix * (us2f(s[0]) + bs[0]) + om * (us2f(s[4]) + bs[4]) + q0) * inv_s;
  float a1 = (mix * (us2f(s[1]) + bs[1]) + om * (us2f(s[5]) + bs[5]) + q1) * inv_s;
  float a2 = (mix * (us2f(s[2]) + bs[2]) + om * (us2f(s[6]) + bs[6]) + q2) * inv_s;
  float a3 = (mix * (us2f(s[3]) + bs[3]) + om * (us2f(s[7]) + bs[7]) + q3) * inv_s;
  const float mx = fmaxf(fmaxf(a0, a1), fmaxf(a2, a3));
  const float e0 = expf(a0 - mx), e1 = expf(a1 - mx);
  const float e2 = expf(a2 - mx), e3 = expf(a3 - mx);
  const float rs = 1.f / (e0 + e1 + e2 + e3);
  ushort4 pk;
  pk.x = f2us(e0 * rs); pk.y = f2us(e1 * rs);
  pk.z = f2us(e2 * rs); pk.w = f2us(e3 * rs);
  *(ushort4*)(w + (size_t)b * KPACK + n * 4) = pk;
}

// ---------------------------------------------------------------------------
__global__ __launch_bounds__(256)
void sentinel_kernel(float* __restrict__ out, float val) {
  const size_t i = (size_t)blockIdx.x * 256 + threadIdx.x;
  if (i < OUT_N) out[i] = val;
}

// ---------------------------------------------------------------------------
extern "C" void kernel_launch(void* const* d_in, const int* in_sizes, int n_in,
                              void* d_out, int out_size, void* d_ws, size_t ws_size,
                              hipStream_t stream)
{
  static const int EXP[16] = {2097152, 8388608, 16384, 65536, 65536, 4096, 4096,
                              64, 1, 256, 4096, 64, 4096, 64, 16384000, 1000};
  bool ok = (n_in == 16) && (out_size == OUT_N);
  if (ok) for (int i = 0; i < 16; ++i) ok = ok && (in_sizes[i] == EXP[i]);
  float* out32 = (float*)d_out;
  if (!ok) {
    sentinel_kernel<<<dim3(16000), dim3(256), 0, stream>>>(out32, 8192.f);
    return;
  }

  const float* x_f    = (const float*)d_in[0];
  const float* Win_f  = (const float*)d_in[1];
  const float* bin_f  = (const float*)d_in[2];
  const float* adjW_f = (const float*)d_in[3];
  const float* Vs_f   = (const float*)d_in[5];
  const float* sem_f  = (const float*)d_in[6];
  const float* mw_f   = (const float*)d_in[7];
  const float* mb_f   = (const float*)d_in[8];
  const float* bas_f  = (const float*)d_in[9];
  const float* qw_f   = (const float*)d_in[10];
  const float* qb_f   = (const float*)d_in[11];
  const float* kw_f   = (const float*)d_in[12];
  const float* kb_f   = (const float*)d_in[13];
  const float* Wout_f = (const float*)d_in[14];
  const float* bout_f = (const float*)d_in[15];

  // adaptive batch chunk from ws_size (>= 12.4 MB fallback always fits)
  int BCH = 1024;
  {
    auto need = [](size_t b) {
      size_t ts = 4718592 > 4608 * b ? 4718592 : 4608 * b;  // T union scores
      return (size_t)32768 + 2359296 + 2097152 + ts + 1024 * b + 2048 * b;
    };
    if (ws_size >= need(4096)) BCH = 4096;
    else if (ws_size >= need(2048)) BCH = 2048;
  }
  const int NCH = B_BATCH / BCH;
  if (ws_size < (size_t)12353536) {
    sentinel_kernel<<<dim3(16000), dim3(256), 0, stream>>>(
        out32, 16.f * (float)(ws_size >> 20));
    return;
  }

  uint8_t* ws = (uint8_t*)d_ws;
  float* adjw   = (float*)(ws + 0);          // 4 KB
  int*   adjidx = (int*)  (ws + 4096);       // 4 KB
  float* vecs   = (float*)(ws + 8192);       // 2304 B
  float* qbK    = (float*)(ws + 10496);      // 16 B
  float* misc   = (float*)(ws + 10560);      // 4 B
  float* bias9  = (float*)(ws + 12288);      // 9216 B
  float* biasc  = (float*)(ws + 21504);      // 4000 B
  size_t off = 32768;
  unsigned short* U  = (unsigned short*)(ws + off); off += 2359296;
  unsigned short* PT = (unsigned short*)(ws + off); off += 2097152;
  float*          T  = (float*)(ws + off);                       // union:
  unsigned short* sc = (unsigned short*)(ws + off);              // T | scores
  off += (4718592 > (size_t)4608 * BCH ? 4718592 : (size_t)4608 * BCH);
  unsigned short* xb = (unsigned short*)(ws + off); off += (size_t)1024 * BCH;
  unsigned short* wq = (unsigned short*)(ws + off);

  setup_kernel<<<dim3(1), dim3(256), 0, stream>>>(
      adjW_f, bas_f, qw_f, qb_f, kw_f, kb_f, Vs_f, sem_f, mw_f, mb_f,
      bin_f, bout_f, adjw, adjidx, vecs, qbK, misc, bias9, biasc);
  build_T_kernel<<<dim3(256), dim3(512), 0, stream>>>(Win_f, vecs, T);
  build_U_kernel<<<dim3(256), dim3(512), 0, stream>>>(T, adjw, adjidx, U);
  build_PT_kernel<<<dim3(1024), dim3(256), 0, stream>>>(Wout_f, bas_f, PT);

  for (int ch = 0; ch < NCH; ++ch) {
    const size_t row0 = (size_t)ch * BCH;
    convert_x_kernel<<<dim3(BCH / 4), dim3(256), 0, stream>>>(
        x_f + row0 * F_IN, xb);
    gemm_bt<F_IN, false><<<dim3(BCH / 128, SCOLS / 64), dim3(256), 0, stream>>>(
        xb, U, sc, nullptr, SCOLS, nullptr);
    softmax_kernel<<<dim3(BCH), dim3(256), 0, stream>>>(sc, bias9, qbK, misc, wq);
    gemm_bt<KPACK, true><<<dim3(BCH / 128, KPACK / 64), dim3(256), 0, stream>>>(
        wq, PT, nullptr, out32 + row0 * C_OUT, C_OUT, biasc);
  }
}

// Round 3
// 243.202 us; speedup vs baseline: 1.0378x; 1.0019x over previous
//
#include <hip/hip_runtime.h>
#include <stdint.h>
#include <stddef.h>

// ============================================================================
// R11: evidence says ~200 us of dur_us is harness workspace re-poison (5x
// 268 MB fillBuffer @ ~40 us in top-5); our kernels are ~45-55 us. Remaining
// controllable items: (a) setup_kernel's uncoalesced k_w reads (256-B lane
// stride) + gathered b_in reads -> coalesced LDS staging with stride-65
// padding (stride-64 would be full same-bank serialization), arithmetic
// order preserved (bit-identical). (b) convert_x folded into build_PT when
// BCH==4096 (1024 blocks x 2048 floats exactly cover x) -> one fewer launch.
// gemm_bt unchanged from R10 (T2 swizzle + T4 counted vmcnt).
// ============================================================================

typedef __attribute__((ext_vector_type(8))) __bf16 bf16x8;
typedef __attribute__((ext_vector_type(4))) float  floatx4;

#define N_NODES 256
#define F_IN    512
#define B_BATCH 4096
#define C_OUT   1000
#define NT      9
#define SCOLS   (N_NODES * NT)   // 2304
#define KPACK   (N_NODES * 4)    // 1024
#define OUT_N   4096000

__device__ __forceinline__ unsigned short f2us(float f) {  // bf16 RNE
  unsigned int v; __builtin_memcpy(&v, &f, sizeof(v));
  unsigned int r = (v + 0x7FFFu + ((v >> 16) & 1u)) >> 16;
  return (unsigned short)r;
}
__device__ __forceinline__ float us2f(unsigned short u) {
  unsigned int v = ((unsigned int)u) << 16;
  float f; __builtin_memcpy(&f, &v, sizeof(f)); return f;
}
__device__ __forceinline__ void async_ld16(const void* g, void* l) {
  __builtin_amdgcn_global_load_lds(
      (const __attribute__((address_space(1))) unsigned int*)g,
      (__attribute__((address_space(3))) unsigned int*)l, 16, 0, 0);
}

// ---------------------------------------------------------------------------
// Kernel 1: adjacency + folds + bias9 + biasc. One block, 256 threads. fp32 in.
// R11: k_w and b_in staged to LDS coalesced (stride-65 rows: bank = (row+col)
// mod 32 varies across lanes; stride-64 would put every row at the same bank).
// ---------------------------------------------------------------------------
__global__ __launch_bounds__(256)
void setup_kernel(const float* __restrict__ adj_w,
                  const float* __restrict__ basis,
                  const float* __restrict__ q_w,
                  const float* __restrict__ q_b,
                  const float* __restrict__ k_w,
                  const float* __restrict__ k_b,
                  const float* __restrict__ V_slow,
                  const float* __restrict__ sem_mem,
                  const float* __restrict__ mix_w,
                  const float* __restrict__ mix_b,
                  const float* __restrict__ b_in,
                  const float* __restrict__ b_out,
                  float* __restrict__ adjw, int* __restrict__ adjidx,
                  float* __restrict__ vecs,   // [9][64]
                  float* __restrict__ qbK,    // [4]
                  float* __restrict__ misc,   // [0]=mix_b
                  float* __restrict__ bias9,  // [256][9]
                  float* __restrict__ biasc)  // [1000]
{
  __shared__ float K4[4 * 64];
  __shared__ float KQ[4 * 64];
  __shared__ float A1s[4 * 64];
  __shared__ float vecsS[9 * 64];
  __shared__ float adjwS[256 * 4];
  __shared__ int   adjidxS[256 * 4];
  __shared__ float kwS[64 * 65];     // k_w rows, stride 65 (16.6 KB)
  __shared__ float binS[256 * 65];   // b_in rows, stride 65 (66.6 KB)
  const int tid = threadIdx.x;

  for (int i = tid; i < C_OUT; i += 256) biasc[i] = b_out[i];
  // coalesced staging: global reads contiguous, LDS rows padded to 65
  for (int i = tid; i < 64 * 64; i += 256)
    kwS[(i >> 6) * 65 + (i & 63)] = k_w[i];
  for (int i = tid; i < 256 * 64; i += 256)
    binS[(i >> 6) * 65 + (i & 63)] = b_in[i];

  // grid adjacency: order up, down, left, right == _grid_structs
  {
    const int n = tid, r = n >> 4, c = n & 15;
    int nb[4]; int cnt = 0;
    if (r > 0)  nb[cnt++] = n - 16;
    if (r < 15) nb[cnt++] = n + 16;
    if (c > 0)  nb[cnt++] = n - 1;
    if (c < 15) nb[cnt++] = n + 1;
    float wv[4] = {0.f, 0.f, 0.f, 0.f};
    float s = 0.f;
    for (int i = 0; i < cnt; ++i) {
      float sg = 1.f / (1.f + expf(-adj_w[(size_t)n * 256 + nb[i]]));
      wv[i] = sg; s += sg;
    }
    float deg = fmaxf(s, 1e-6f);
    int over = 0;
    for (int i = 0; i < cnt; ++i) { wv[i] /= deg; over += (wv[i] > 0.1f) ? 1 : 0; }
    if (over < 1) wv[0] = fmaxf(wv[0], 0.5f);
    for (int i = cnt; i < 4; ++i) nb[i] = n;    // pad, weight 0
    for (int i = 0; i < 4; ++i) {
      adjw[n * 4 + i] = wv[i];  adjidx[n * 4 + i] = nb[i];
      adjwS[n * 4 + i] = wv[i]; adjidxS[n * 4 + i] = nb[i];
    }
  }
  __syncthreads();   // kwS/binS staged
  // K4[j][d] = basis_j · k_w[d,:] + k_b[d]   (k_w from LDS, same order)
  {
    const int j = tid >> 6, d = tid & 63;
    float acc = k_b[d];
    for (int e = 0; e < 64; ++e) acc += basis[j * 64 + e] * kwS[d * 65 + e];
    K4[j * 64 + d] = acc;
  }
  __syncthreads();
  // KQ[j][e] = sum_d K4[j][d] q_w[d,e];  qbK[j] = q_b·K4_j;  mix_b
  {
    const int j = tid >> 6, e = tid & 63;
    float acc = 0.f;
    for (int d = 0; d < 64; ++d) acc += K4[j * 64 + d] * q_w[d * 64 + e];
    KQ[j * 64 + e] = acc;
    if (tid < 4) {
      float q = 0.f;
      for (int d = 0; d < 64; ++d) q += q_b[d] * K4[tid * 64 + d];
      qbK[tid] = q;
    }
    if (tid == 0) misc[0] = mix_b[0];
  }
  __syncthreads();
  // A1[j][e] = sum_d KQ[j][d] V_slow[d,e];  mw2[e] = sum_d mix_w[d] V_slow[d,e]
  {
    const int j = tid >> 6, e = tid & 63;
    float acc = 0.f;
    for (int d = 0; d < 64; ++d) acc += KQ[j * 64 + d] * V_slow[d * 64 + e];
    A1s[j * 64 + e] = acc;
    vecsS[j * 64 + e] = acc;
    if (tid < 64) {
      float mm = 0.f;
      for (int d = 0; d < 64; ++d) mm += mix_w[d] * V_slow[d * 64 + tid];
      vecsS[8 * 64 + tid] = mm;
    }
  }
  __syncthreads();
  // A2[j][f] = sum_e A1[j][e] sem_mem[e,f]
  {
    const int j = tid >> 6, f = tid & 63;
    float acc = 0.f;
    for (int e = 0; e < 64; ++e) acc += A1s[j * 64 + e] * sem_mem[e * 64 + f];
    vecsS[(4 + j) * 64 + f] = acc;
  }
  __syncthreads();
  for (int i = tid; i < NT * 64; i += 256) vecs[i] = vecsS[i];
  // bias9[n][t] = sum_d (sum_k aw*b_in[idx*64+d]) * vec_t[d]   (b_in from LDS)
  {
    const int n = tid;
    float bt[9] = {0,0,0,0,0,0,0,0,0};
    for (int d = 0; d < 64; ++d) {
      float v = 0.f;
      for (int k = 0; k < 4; ++k)
        v += adjwS[n * 4 + k] * binS[adjidxS[n * 4 + k] * 65 + d];
      #pragma unroll
      for (int t = 0; t < 9; ++t) bt[t] += v * vecsS[t * 64 + d];
    }
    for (int t = 0; t < 9; ++t) bias9[n * 9 + t] = bt[t];
  }
}

// ---------------------------------------------------------------------------
// Kernel 2: x chunk -> bf16 (8 elems/thread)  — only used when BCH < 4096
// ---------------------------------------------------------------------------
__global__ __launch_bounds__(256)
void convert_x_kernel(const float* __restrict__ x, unsigned short* __restrict__ xb)
{
  const size_t i0 = ((size_t)blockIdx.x * 256 + threadIdx.x) * 8;
  const float4 a = *(const float4*)(x + i0);
  const float4 b = *(const float4*)(x + i0 + 4);
  ushort4 o0, o1;
  o0.x = f2us(a.x); o0.y = f2us(a.y); o0.z = f2us(a.z); o0.w = f2us(a.w);
  o1.x = f2us(b.x); o1.y = f2us(b.y); o1.z = f2us(b.z); o1.w = f2us(b.w);
  *(ushort4*)(xb + i0)     = o0;
  *(ushort4*)(xb + i0 + 4) = o1;
}

// ---------------------------------------------------------------------------
// Kernel 3: T[m*9+t][f] = sum_d vec_t[d] * W_in[m*64+d, f]   (fp32)
// ---------------------------------------------------------------------------
__global__ __launch_bounds__(512)
void build_T_kernel(const float* __restrict__ W_in,
                    const float* __restrict__ vecs,
                    float* __restrict__ T)
{
  __shared__ float vl[NT * 64];
  const int m = blockIdx.x, f = threadIdx.x;
  for (int i = threadIdx.x; i < NT * 64; i += 512) vl[i] = vecs[i];
  __syncthreads();
  float acc[NT] = {0,0,0,0,0,0,0,0,0};
  for (int d = 0; d < 64; ++d) {
    float wv = W_in[(size_t)(m * 64 + d) * F_IN + f];
    #pragma unroll
    for (int t = 0; t < NT; ++t) acc[t] += wv * vl[t * 64 + d];
  }
  for (int t = 0; t < NT; ++t) T[(size_t)(m * NT + t) * F_IN + f] = acc[t];
}

// ---------------------------------------------------------------------------
// Kernel 4: U[n*9+t][f] = sum_k adjw[n][k] * T[idx[n][k]*9+t][f]  (bf16)
// ---------------------------------------------------------------------------
__global__ __launch_bounds__(512)
void build_U_kernel(const float* __restrict__ T,
                    const float* __restrict__ adjw,
                    const int* __restrict__ adjidx,
                    unsigned short* __restrict__ U)
{
  const int n = blockIdx.x, f = threadIdx.x;
  const float w0 = adjw[n * 4 + 0], w1 = adjw[n * 4 + 1];
  const float w2 = adjw[n * 4 + 2], w3 = adjw[n * 4 + 3];
  const int i0 = adjidx[n * 4 + 0], i1 = adjidx[n * 4 + 1];
  const int i2 = adjidx[n * 4 + 2], i3 = adjidx[n * 4 + 3];
  #pragma unroll
  for (int t = 0; t < NT; ++t) {
    float u = w0 * T[(size_t)(i0 * NT + t) * F_IN + f]
            + w1 * T[(size_t)(i1 * NT + t) * F_IN + f]
            + w2 * T[(size_t)(i2 * NT + t) * F_IN + f]
            + w3 * T[(size_t)(i3 * NT + t) * F_IN + f];
    U[(size_t)(n * NT + t) * F_IN + f] = f2us(u);
  }
}

// ---------------------------------------------------------------------------
// Kernel 5: PT[c][n*4+j] = basis_j · W_out[c, n*64:+64]  (bf16); pad rows zero
// R11: optionally also converts x chunk c (2048 floats) -> xb, replacing the
// separate convert_x launch when BCH == 4096 (1024 blocks cover x exactly).
// ---------------------------------------------------------------------------
__global__ __launch_bounds__(256)
void build_PT_kernel(const float* __restrict__ W_out,
                     const float* __restrict__ basis,
                     unsigned short* __restrict__ PT,
                     const float* __restrict__ xc,        // may be null
                     unsigned short* __restrict__ xbo)
{
  const int c = blockIdx.x, tid = threadIdx.x;
  if (xc) {  // fused convert_x: block c handles elements [c*2048, c*2048+2048)
    const size_t i0 = ((size_t)c * 256 + tid) * 8;
    const float4 a = *(const float4*)(xc + i0);
    const float4 b = *(const float4*)(xc + i0 + 4);
    ushort4 o0, o1;
    o0.x = f2us(a.x); o0.y = f2us(a.y); o0.z = f2us(a.z); o0.w = f2us(a.w);
    o1.x = f2us(b.x); o1.y = f2us(b.y); o1.z = f2us(b.z); o1.w = f2us(b.w);
    *(ushort4*)(xbo + i0)     = o0;
    *(ushort4*)(xbo + i0 + 4) = o1;
  }
  if (c >= C_OUT) {
    for (int i = tid; i < KPACK; i += 256) PT[(size_t)c * KPACK + i] = 0;
    return;
  }
  __shared__ __align__(16) float row[16384];   // one W_out row, 64 KB LDS
  __shared__ float bas[4 * 64];
  const float4* src = (const float4*)(W_out + (size_t)c * 16384);
  float4* dst = (float4*)row;
  for (int i = tid; i < 4096; i += 256) dst[i] = src[i];
  bas[tid] = basis[tid];
  __syncthreads();
  const int n = tid;
  float a0 = 0.f, a1 = 0.f, a2 = 0.f, a3 = 0.f;
  for (int dd = 0; dd < 64; ++dd) {
    int d = (dd + n) & 63;                  // rotate: 2-way banking (free)
    float wv = row[n * 64 + d];
    a0 += wv * bas[0 * 64 + d];
    a1 += wv * bas[1 * 64 + d];
    a2 += wv * bas[2 * 64 + d];
    a3 += wv * bas[3 * 64 + d];
  }
  unsigned short* p = PT + (size_t)c * KPACK + n * 4;
  p[0] = f2us(a0); p[1] = f2us(a1); p[2] = f2us(a2); p[3] = f2us(a3);
}

// ---------------------------------------------------------------------------
// 128x64 bf16 MFMA GEMM, C = A @ B^T.  (unchanged from R10)
// T2: granule swizzle g^=(row&7) — LDS dest of global_load_lds stays linear,
//     the GLOBAL source granule is inverse-permuted (XOR is an involution),
//     reads apply the same XOR. 16-way bank conflict -> all 32 banks active.
// T4: counted s_waitcnt vmcnt(6) + raw s_barrier pair per K-step; prefetch
//     stays in flight across barriers.
// ---------------------------------------------------------------------------
template <int K, bool FINAL>
__global__ __launch_bounds__(256)
void gemm_bt(const unsigned short* __restrict__ A,
             const unsigned short* __restrict__ B,
             unsigned short* __restrict__ Cb, float* __restrict__ Cf,
             int ncol, const float* __restrict__ biasf)
{
  __shared__ __align__(16) unsigned short As[2][128 * 64];  // 2 x 16 KB
  __shared__ __align__(16) unsigned short Bs[2][64 * 64];   // 2 x  8 KB
  const int tid  = threadIdx.x;
  const int lane = tid & 63;
  const int wave = tid >> 6;
  const int m0 = blockIdx.x * 128;
  const int n0 = blockIdx.y * 64;
  const int wm = (wave >> 1) * 64;
  const int wn = (wave & 1) * 32;

  floatx4 acc[4][2];
  #pragma unroll
  for (int i = 0; i < 4; ++i)
    #pragma unroll
    for (int j = 0; j < 2; ++j) acc[i][j] = (floatx4){0.f, 0.f, 0.f, 0.f};

  const int NK = K / 64;

  auto stage = [&](int s, int kt) {
    const int k0 = kt * 64;
    #pragma unroll
    for (int it = 0; it < 4; ++it) {           // A: 128 rows x 8 granules
      const int chunk = it * 256 + tid;
      const int r = chunk >> 3, g = chunk & 7;
      async_ld16(A + (size_t)(m0 + r) * K + k0 + ((g ^ (r & 7)) << 3),
                 &As[s][(it * 256 + wave * 64) * 8]);
    }
    #pragma unroll
    for (int it = 0; it < 2; ++it) {           // B: 64 rows x 8 granules
      const int chunk = it * 256 + tid;
      const int r = chunk >> 3, g = chunk & 7;
      async_ld16(B + (size_t)(n0 + r) * K + k0 + ((g ^ (r & 7)) << 3),
                 &Bs[s][(it * 256 + wave * 64) * 8]);
    }
  };

  stage(0, 0);                                 // 6 loads/thread in flight
  int cur = 0;

  for (int kt = 0; kt < NK; ++kt) {
    if (kt + 1 < NK) {
      stage(cur ^ 1, kt + 1);                  // outstanding: 12
      asm volatile("s_waitcnt vmcnt(6)" ::: "memory");
    } else {
      asm volatile("s_waitcnt vmcnt(0)" ::: "memory");
    }
    __builtin_amdgcn_s_barrier();              // all waves' kt loads resident

    const int lrow = lane & 15;
    const int ghi  = lane >> 4;
    #pragma unroll
    for (int kk = 0; kk < 2; ++kk) {
      const int gbase = kk * 4 + ghi;
      bf16x8 af[4], bfr[2];
      #pragma unroll
      for (int i = 0; i < 4; ++i) {
        const int row = wm + i * 16 + lrow;
        af[i] = *(const bf16x8*)&As[cur][row * 64 + ((gbase ^ (row & 7)) << 3)];
      }
      #pragma unroll
      for (int j = 0; j < 2; ++j) {
        const int row = wn + j * 16 + lrow;
        bfr[j] = *(const bf16x8*)&Bs[cur][row * 64 + ((gbase ^ (row & 7)) << 3)];
      }
      #pragma unroll
      for (int i = 0; i < 4; ++i)
        #pragma unroll
        for (int j = 0; j < 2; ++j)
          acc[i][j] = __builtin_amdgcn_mfma_f32_16x16x32_bf16(af[i], bfr[j], acc[i][j], 0, 0, 0);
    }
    if (kt + 1 < NK) {
      __builtin_amdgcn_s_barrier();
      cur ^= 1;
    }
  }

  // epilogue: C/D layout col = lane&15, row = (lane>>4)*4 + reg
  const int rq = (lane >> 4) * 4;
  const int cq = lane & 15;
  #pragma unroll
  for (int j = 0; j < 2; ++j) {
    const int col = n0 + wn + j * 16 + cq;
    if (FINAL && col >= ncol) continue;
    const float bv2 = FINAL ? biasf[col] : 0.f;
    #pragma unroll
    for (int i = 0; i < 4; ++i)
      #pragma unroll
      for (int r = 0; r < 4; ++r) {
        const int rowi = m0 + wm + i * 16 + rq + r;
        if (FINAL) Cf[(size_t)rowi * ncol + col] = acc[i][j][r] + bv2;
        else       Cb[(size_t)rowi * ncol + col] = f2us(acc[i][j][r]);
      }
  }
}

// ---------------------------------------------------------------------------
// Kernel 7: per-(b,n) mix/attn/softmax -> w bf16 [BCH][1024]
// ---------------------------------------------------------------------------
__global__ __launch_bounds__(256)
void softmax_kernel(const unsigned short* __restrict__ scores,  // bf16 [BCH][2304]
                    const float* __restrict__ bias9,
                    const float* __restrict__ qbK,
                    const float* __restrict__ misc,
                    unsigned short* __restrict__ w)
{
  const int b = blockIdx.x, n = threadIdx.x;
  const unsigned short* s = scores + (size_t)b * SCOLS + n * NT;
  const float* bs = bias9 + n * NT;
  const float mixb = misc[0];
  const float q0 = qbK[0], q1 = qbK[1], q2 = qbK[2], q3 = qbK[3];
  const float mix = 1.f / (1.f + expf(-(us2f(s[8]) + bs[8] + mixb)));
  const float om = 1.f - mix;
  const float inv_s = 1.f / (8.f + 1e-8f);
  float a0 = (mix * (us2f(s[0]) + bs[0]) + om * (us2f(s[4]) + bs[4]) + q0) * inv_s;
  float a1 = (mix * (us2f(s[1]) + bs[1]) + om * (us2f(s[5]) + bs[5]) + q1) * inv_s;
  float a2 = (mix * (us2f(s[2]) + bs[2]) + om * (us2f(s[6]) + bs[6]) + q2) * inv_s;
  float a3 = (mix * (us2f(s[3]) + bs[3]) + om * (us2f(s[7]) + bs[7]) + q3) * inv_s;
  const float mx = fmaxf(fmaxf(a0, a1), fmaxf(a2, a3));
  const float e0 = expf(a0 - mx), e1 = expf(a1 - mx);
  const float e2 = expf(a2 - mx), e3 = expf(a3 - mx);
  const float rs = 1.f / (e0 + e1 + e2 + e3);
  ushort4 pk;
  pk.x = f2us(e0 * rs); pk.y = f2us(e1 * rs);
  pk.z = f2us(e2 * rs); pk.w = f2us(e3 * rs);
  *(ushort4*)(w + (size_t)b * KPACK + n * 4) = pk;
}

// ---------------------------------------------------------------------------
__global__ __launch_bounds__(256)
void sentinel_kernel(float* __restrict__ out, float val) {
  const size_t i = (size_t)blockIdx.x * 256 + threadIdx.x;
  if (i < OUT_N) out[i] = val;
}

// ---------------------------------------------------------------------------
extern "C" void kernel_launch(void* const* d_in, const int* in_sizes, int n_in,
                              void* d_out, int out_size, void* d_ws, size_t ws_size,
                              hipStream_t stream)
{
  static const int EXP[16] = {2097152, 8388608, 16384, 65536, 65536, 4096, 4096,
                              64, 1, 256, 4096, 64, 4096, 64, 16384000, 1000};
  bool ok = (n_in == 16) && (out_size == OUT_N);
  if (ok) for (int i = 0; i < 16; ++i) ok = ok && (in_sizes[i] == EXP[i]);
  float* out32 = (float*)d_out;
  if (!ok) {
    sentinel_kernel<<<dim3(16000), dim3(256), 0, stream>>>(out32, 8192.f);
    return;
  }

  const float* x_f    = (const float*)d_in[0];
  const float* Win_f  = (const float*)d_in[1];
  const float* bin_f  = (const float*)d_in[2];
  const float* adjW_f = (const float*)d_in[3];
  const float* Vs_f   = (const float*)d_in[5];
  const float* sem_f  = (const float*)d_in[6];
  const float* mw_f   = (const float*)d_in[7];
  const float* mb_f   = (const float*)d_in[8];
  const float* bas_f  = (const float*)d_in[9];
  const float* qw_f   = (const float*)d_in[10];
  const float* qb_f   = (const float*)d_in[11];
  const float* kw_f   = (const float*)d_in[12];
  const float* kb_f   = (const float*)d_in[13];
  const float* Wout_f = (const float*)d_in[14];
  const float* bout_f = (const float*)d_in[15];

  // adaptive batch chunk from ws_size (>= 12.4 MB fallback always fits)
  int BCH = 1024;
  {
    auto need = [](size_t b) {
      size_t ts = 4718592 > 4608 * b ? 4718592 : 4608 * b;  // T union scores
      return (size_t)32768 + 2359296 + 2097152 + ts + 1024 * b + 2048 * b;
    };
    if (ws_size >= need(4096)) BCH = 4096;
    else if (ws_size >= need(2048)) BCH = 2048;
  }
  const int NCH = B_BATCH / BCH;
  if (ws_size < (size_t)12353536) {
    sentinel_kernel<<<dim3(16000), dim3(256), 0, stream>>>(
        out32, 16.f * (float)(ws_size >> 20));
    return;
  }

  uint8_t* ws = (uint8_t*)d_ws;
  float* adjw   = (float*)(ws + 0);          // 4 KB
  int*   adjidx = (int*)  (ws + 4096);       // 4 KB
  float* vecs   = (float*)(ws + 8192);       // 2304 B
  float* qbK    = (float*)(ws + 10496);      // 16 B
  float* misc   = (float*)(ws + 10560);      // 4 B
  float* bias9  = (float*)(ws + 12288);      // 9216 B
  float* biasc  = (float*)(ws + 21504);      // 4000 B
  size_t off = 32768;
  unsigned short* U  = (unsigned short*)(ws + off); off += 2359296;
  unsigned short* PT = (unsigned short*)(ws + off); off += 2097152;
  float*          T  = (float*)(ws + off);                       // union:
  unsigned short* sc = (unsigned short*)(ws + off);              // T | scores
  off += (4718592 > (size_t)4608 * BCH ? 4718592 : (size_t)4608 * BCH);
  unsigned short* xb = (unsigned short*)(ws + off); off += (size_t)1024 * BCH;
  unsigned short* wq = (unsigned short*)(ws + off);

  setup_kernel<<<dim3(1), dim3(256), 0, stream>>>(
      adjW_f, bas_f, qw_f, qb_f, kw_f, kb_f, Vs_f, sem_f, mw_f, mb_f,
      bin_f, bout_f, adjw, adjidx, vecs, qbK, misc, bias9, biasc);
  build_T_kernel<<<dim3(256), dim3(512), 0, stream>>>(Win_f, vecs, T);
  build_U_kernel<<<dim3(256), dim3(512), 0, stream>>>(T, adjw, adjidx, U);
  // BCH==4096: build_PT's 1024 blocks also convert the whole x (exact cover)
  build_PT_kernel<<<dim3(1024), dim3(256), 0, stream>>>(
      Wout_f, bas_f, PT, (BCH == 4096) ? x_f : nullptr, xb);

  for (int ch = 0; ch < NCH; ++ch) {
    const size_t row0 = (size_t)ch * BCH;
    if (BCH != 4096)
      convert_x_kernel<<<dim3(BCH / 4), dim3(256), 0, stream>>>(
          x_f + row0 * F_IN, xb);
    gemm_bt<F_IN, false><<<dim3(BCH / 128, SCOLS / 64), dim3(256), 0, stream>>>(
        xb, U, sc, nullptr, SCOLS, nullptr);
    softmax_kernel<<<dim3(BCH), dim3(256), 0, stream>>>(sc, bias9, qbK, misc, wq);
    gemm_bt<KPACK, true><<<dim3(BCH / 128, KPACK / 64), dim3(256), 0, stream>>>(
        wq, PT, nullptr, out32 + row0 * C_OUT, C_OUT, biasc);
  }
}